// Round 1
// baseline (214.236 us; speedup 1.0000x reference)
//
#include <hip/hip_runtime.h>
#include <stdint.h>

// Problem constants (fixed by setup_inputs)
#define BATCH 32
#define CH    256
#define MID   64
#define HW    3136           // 56*56
#define HWV   784            // float4 vectors per plane (3136/4)
#define NPLANES (BATCH * CH) // 8192

typedef __attribute__((ext_vector_type(4))) float fvec4;

// -----------------------------------------------------------------------------
// K1: global average pool. ONE WAVE PER PLANE (no LDS, no __syncthreads, no
// atomics, no memset). Each wave streams 784 contiguous fvec4 (12.25 iters of
// 1 KiB/instruction), wave-reduces via shuffle, lane 0 stores pooled[p].
// 2048 blocks x 4 waves = 8192 waves = 8192 planes exactly.
// -----------------------------------------------------------------------------
__global__ __launch_bounds__(256) void se_pool(const fvec4* __restrict__ x,
                                               float* __restrict__ pooled) {
    const int gw   = (blockIdx.x << 2) + (threadIdx.x >> 6); // global wave = plane
    const int lane = threadIdx.x & 63;

    const fvec4* base = x + (size_t)gw * HWV;
    float s = 0.0f;
    #pragma unroll 4
    for (int i = lane; i < HWV; i += 64) {
        fvec4 v = base[i];
        s += (v.x + v.y) + (v.z + v.w);
    }
    #pragma unroll
    for (int off = 32; off > 0; off >>= 1) s += __shfl_down(s, off, 64);
    if (lane == 0) pooled[gw] = s * (1.0f / (float)HW);
}

// -----------------------------------------------------------------------------
// K2: the whole SE MLP for one batch element per block (32 blocks, ~3 us).
// buf holds pooled[b,c] on entry and gate[b,c] on exit (in-place is safe:
// each block owns its 256-float slice; pooled is staged to LDS before the
// overwrite). Weights (64 KB + 64 KB) are L2-hot broadcast reads.
//   h_m  = relu(b1[m] + sum_c pooled[c] * w1[m,c])   (4-way c-split over waves)
//   y_c  = b2[c] + sum_m h_m * w2[c,m]
//   gate = relu6(y + 3) / 6
// -----------------------------------------------------------------------------
__global__ __launch_bounds__(256) void se_mlp(float* __restrict__ buf,
                                              const float* __restrict__ w1,
                                              const float* __restrict__ b1,
                                              const float* __restrict__ w2,
                                              const float* __restrict__ b2) {
    const int b = blockIdx.x;
    const int t = threadIdx.x;

    __shared__ float pl[CH];
    __shared__ float hq[4][MID];
    __shared__ float hsh[MID];

    pl[t] = buf[b * CH + t];
    __syncthreads();

    // squeeze: wave q handles c in [q*64, q*64+64) for hidden unit m = lane
    const int m = t & 63, q = t >> 6;
    const float* w1r = w1 + m * CH + q * 64;
    const float* plq = pl + q * 64;
    float acc = 0.0f;
    #pragma unroll 8
    for (int c = 0; c < 64; ++c) acc += plq[c] * w1r[c];
    hq[q][m] = acc;
    __syncthreads();

    if (t < MID) {
        hsh[t] = fmaxf(hq[0][t] + hq[1][t] + hq[2][t] + hq[3][t] + b1[t], 0.0f);
    }
    __syncthreads();

    // expand: thread t = output channel c
    const float* w2r = w2 + t * MID;
    float y = b2[t];
    #pragma unroll 8
    for (int mm = 0; mm < MID; ++mm) y += hsh[mm] * w2r[mm];
    buf[b * CH + t] = fminf(fmaxf(y + 3.0f, 0.0f), 6.0f) * 0.16666667f;
}

// -----------------------------------------------------------------------------
// K3: pure streaming scale. gate[p] is a wave-uniform broadcast load; no
// reduce / no sync on the store path. x re-read should hit the 256 MiB L3
// (just fetched by K1); NT stores keep `out` from evicting x.
// -----------------------------------------------------------------------------
__global__ __launch_bounds__(256) void se_scale(const fvec4* __restrict__ x,
                                                const float* __restrict__ gate,
                                                fvec4* __restrict__ out) {
    const int p = blockIdx.x;
    const int t = threadIdx.x;
    const float g = gate[p];

    const fvec4* xb = x + (size_t)p * HWV;
    fvec4* ob = out + (size_t)p * HWV;

    fvec4 v0 = xb[t];
    fvec4 v1 = xb[t + 256];
    fvec4 v2 = xb[t + 512];
    fvec4 v3 = {0.f, 0.f, 0.f, 0.f};
    if (t < 16) v3 = xb[t + 768];

    __builtin_nontemporal_store(v0 * g, ob + t);
    __builtin_nontemporal_store(v1 * g, ob + t + 256);
    __builtin_nontemporal_store(v2 * g, ob + t + 512);
    if (t < 16) __builtin_nontemporal_store(v3 * g, ob + t + 768);
}

extern "C" void kernel_launch(void* const* d_in, const int* in_sizes, int n_in,
                              void* d_out, int out_size, void* d_ws, size_t ws_size,
                              hipStream_t stream) {
    (void)in_sizes; (void)n_in; (void)out_size; (void)ws_size;

    const float* x  = (const float*)d_in[0];
    const float* w1 = (const float*)d_in[1];
    const float* b1 = (const float*)d_in[2];
    const float* w2 = (const float*)d_in[3];
    const float* b2 = (const float*)d_in[4];

    // workspace: 8192 floats (32 KB). pooled on entry to se_mlp, gate on exit.
    float* buf = (float*)d_ws;

    se_pool<<<NPLANES / 4, 256, 0, stream>>>((const fvec4*)x, buf);
    se_mlp<<<BATCH, 256, 0, stream>>>(buf, w1, b1, w2, b2);
    se_scale<<<NPLANES, 256, 0, stream>>>((const fvec4*)x, buf, (fvec4*)d_out);
}

// Round 4
// 211.397 us; speedup vs baseline: 1.0134x; 1.0134x over previous
//
#include <hip/hip_runtime.h>
#include <stdint.h>

// Problem constants (fixed by setup_inputs)
#define BATCH 32
#define CH    256
#define MID   64
#define HW    3136           // 56*56
#define HWV   784            // float4 vectors per plane (3136/4 = 12*64 + 16)
#define NPLANES (BATCH * CH) // 8192

typedef __attribute__((ext_vector_type(4))) float fvec4;

// -----------------------------------------------------------------------------
// K1: global average pool. One wave per plane; no LDS / sync / atomics.
// Plane assignment is XCD-aligned: block blk (XCD = blk%8) pools planes with
// plane%8 == blk%8, so the per-XCD L2 that streams a plane here is the same
// L2 that re-reads it in se_scale (whose block for plane p also lands on
// XCD p%8).  p = (blk&7) + 8*((blk>>3)*4 + q)  — bijective over [0, 8192).
// -----------------------------------------------------------------------------
__global__ __launch_bounds__(256) void se_pool(const fvec4* __restrict__ x,
                                               float* __restrict__ pooled) {
    const int blk  = blockIdx.x;
    const int q    = threadIdx.x >> 6;   // wave id within block
    const int lane = threadIdx.x & 63;
    const int p    = (blk & 7) + (((blk >> 3) << 2) + q) * 8;

    const fvec4* base = x + (size_t)p * HWV;
    float s = 0.0f;
    #pragma unroll
    for (int i = 0; i < 12; ++i) {               // 12*64 = 768 vectors
        fvec4 v = base[lane + (i << 6)];
        s += (v.x + v.y) + (v.z + v.w);
    }
    if (lane < 16) {                             // tail: vectors 768..783
        fvec4 v = base[lane + 768];
        s += (v.x + v.y) + (v.z + v.w);
    }
    #pragma unroll
    for (int off = 32; off > 0; off >>= 1) s += __shfl_down(s, off, 64);
    if (lane == 0) pooled[p] = s * (1.0f / (float)HW);
}

// -----------------------------------------------------------------------------
// K2: whole SE MLP, one batch element per block (32 blocks, ~4 us).
// buf holds pooled[b,c] on entry, gate[b,c] on exit (block owns its slice).
// -----------------------------------------------------------------------------
__global__ __launch_bounds__(256) void se_mlp(float* __restrict__ buf,
                                              const float* __restrict__ w1,
                                              const float* __restrict__ b1,
                                              const float* __restrict__ w2,
                                              const float* __restrict__ b2) {
    const int b = blockIdx.x;
    const int t = threadIdx.x;

    __shared__ float pl[CH];
    __shared__ float hq[4][MID];
    __shared__ float hsh[MID];

    pl[t] = buf[b * CH + t];
    __syncthreads();

    // squeeze: wave q covers c in [q*64, q*64+64) for hidden unit m = lane
    const int m = t & 63, q = t >> 6;
    const float* w1r = w1 + m * CH + q * 64;
    const float* plq = pl + q * 64;
    float acc = 0.0f;
    #pragma unroll 8
    for (int c = 0; c < 64; ++c) acc += plq[c] * w1r[c];
    hq[q][m] = acc;
    __syncthreads();

    if (t < MID) {
        hsh[t] = fmaxf(hq[0][t] + hq[1][t] + hq[2][t] + hq[3][t] + b1[t], 0.0f);
    }
    __syncthreads();

    // expand: thread t = output channel c; gate overwrites buf in-place
    const float* w2r = w2 + t * MID;
    float y = b2[t];
    #pragma unroll 8
    for (int mm = 0; mm < MID; ++mm) y += hsh[mm] * w2r[mm];
    buf[b * CH + t] = fminf(fmaxf(y + 3.0f, 0.0f), 6.0f) * 0.16666667f;
}

// -----------------------------------------------------------------------------
// K3: pure streaming scale. Plane order is group-of-8 REVERSED so the first
// scale blocks touch the most-recently-pooled (L2/L3-hot) planes, while
// plane%8 == blockIdx%8 keeps each read on the XCD whose L2 pooled it.
// gate[p] is a wave-uniform broadcast; NT stores keep out from evicting x.
// p = (1023 - (blk>>3))*8 + (blk&7)  — bijective over [0, 8192).
// -----------------------------------------------------------------------------
__global__ __launch_bounds__(256) void se_scale(const fvec4* __restrict__ x,
                                                const float* __restrict__ gate,
                                                fvec4* __restrict__ out) {
    const int blk = blockIdx.x;
    const int p   = ((NPLANES / 8 - 1) - (blk >> 3)) * 8 + (blk & 7);
    const int t   = threadIdx.x;
    const float g = gate[p];

    const fvec4* xb = x + (size_t)p * HWV;
    fvec4* ob = out + (size_t)p * HWV;

    fvec4 v0 = xb[t];
    fvec4 v1 = xb[t + 256];
    fvec4 v2 = xb[t + 512];
    fvec4 v3 = {0.f, 0.f, 0.f, 0.f};
    if (t < 16) v3 = xb[t + 768];

    __builtin_nontemporal_store(v0 * g, ob + t);
    __builtin_nontemporal_store(v1 * g, ob + t + 256);
    __builtin_nontemporal_store(v2 * g, ob + t + 512);
    if (t < 16) __builtin_nontemporal_store(v3 * g, ob + t + 768);
}

extern "C" void kernel_launch(void* const* d_in, const int* in_sizes, int n_in,
                              void* d_out, int out_size, void* d_ws, size_t ws_size,
                              hipStream_t stream) {
    (void)in_sizes; (void)n_in; (void)out_size; (void)ws_size;

    const float* x  = (const float*)d_in[0];
    const float* w1 = (const float*)d_in[1];
    const float* b1 = (const float*)d_in[2];
    const float* w2 = (const float*)d_in[3];
    const float* b2 = (const float*)d_in[4];

    // workspace: 8192 floats (32 KB). pooled on entry to se_mlp, gate on exit.
    float* buf = (float*)d_ws;

    se_pool<<<NPLANES / 4, 256, 0, stream>>>((const fvec4*)x, buf);
    se_mlp<<<BATCH, 256, 0, stream>>>(buf, w1, b1, w2, b2);
    se_scale<<<NPLANES, 256, 0, stream>>>((const fvec4*)x, buf, (fvec4*)d_out);
}